// Round 1
// baseline (4094.748 us; speedup 1.0000x reference)
//
#include <hip/hip_runtime.h>
#include <math.h>

// Problem constants
#define B_ 8
#define T_ 50
#define N_ 1000
#define F_ 4
#define G_ 32
#define H_ 256
#define E_ 32000
#define S_ 5
#define R_ 400        // B*T
#define K0_ 32000     // N*G (LSTM0 input size)
#define NG_ 1024      // 4*H
#define KS_ 16        // split-K factor for big GEMM
#define KRANGE_ 2000  // K0_/KS_

static __device__ __forceinline__ float sigm(float x) { return 1.0f / (1.0f + expf(-x)); }

// ---------------------------------------------------------------------------
// Kernel 1: GCN per (b,t). One WG per r=b*50+t. x staged in LDS, agg in LDS
// with ds_add_f32 atomics (lane g = tid&31 -> bank g, conflict-free banking).
// ---------------------------------------------------------------------------
__global__ __launch_bounds__(256, 1) void gcn_kernel(
    const float* __restrict__ x, const int* __restrict__ ei,
    const float* __restrict__ ew, const float* __restrict__ Wg,
    const float* __restrict__ bg, float* __restrict__ Z) {
  __shared__ float4 xs4[N_];          // 16 KB  (x[n][0..3])
  __shared__ float agg[N_ * G_];      // 128 KB
  const int r = blockIdx.x;
  const int tid = threadIdx.x;

  // stage x row-block (coalesced float4)
  const float4* xg = (const float4*)(x + (size_t)r * N_ * F_);
  for (int i = tid; i < N_; i += 256) xs4[i] = xg[i];
  // zero agg
  float4* av = (float4*)agg;
  for (int i = tid; i < N_ * G_ / 4; i += 256) av[i] = make_float4(0.f, 0.f, 0.f, 0.f);

  const int g = tid & 31;
  const float w0 = Wg[0 * G_ + g], w1 = Wg[1 * G_ + g];
  const float w2 = Wg[2 * G_ + g], w3 = Wg[3 * G_ + g];
  __syncthreads();

  const int* src = ei + (size_t)r * 2 * E_;
  const int* dst = src + E_;
  const float* wp = ew + (size_t)r * E_;

  // 4-edge batches per thread for load pipelining; wave = 2 edges x 32 g
  for (int e = (tid >> 5); e < E_; e += 32) {
    int s0 = src[e], s1 = src[e + 8], s2 = src[e + 16], s3 = src[e + 24];
    int d0 = dst[e], d1 = dst[e + 8], d2 = dst[e + 16], d3 = dst[e + 24];
    float we0 = wp[e], we1 = wp[e + 8], we2 = wp[e + 16], we3 = wp[e + 24];
    float4 x0 = xs4[s0], x1 = xs4[s1], x2 = xs4[s2], x3 = xs4[s3];
    float m0 = we0 * (x0.x * w0 + x0.y * w1 + x0.z * w2 + x0.w * w3);
    float m1 = we1 * (x1.x * w0 + x1.y * w1 + x1.z * w2 + x1.w * w3);
    float m2 = we2 * (x2.x * w0 + x2.y * w1 + x2.z * w2 + x2.w * w3);
    float m3 = we3 * (x3.x * w0 + x3.y * w1 + x3.z * w2 + x3.w * w3);
    atomicAdd(&agg[d0 * G_ + g], m0);
    atomicAdd(&agg[d1 * G_ + g], m1);
    atomicAdd(&agg[d2 * G_ + g], m2);
    atomicAdd(&agg[d3 * G_ + g], m3);
  }
  __syncthreads();

  // z = tanh(agg + b_gcn);  k = n*32+g, g = k&31 = tid&31 (256 % 32 == 0)
  const float bgv = bg[g];
  float* Zr = Z + (size_t)r * K0_;
  for (int k = tid; k < K0_; k += 256) Zr[k] = tanhf(agg[k] + bgv);
}

// ---------------------------------------------------------------------------
// Kernel 2: big input GEMM  part[kz] += Z(400x32000) @ Wih0^T(32000x1024)
// fp32, 128x128 tile, 8x8 microtile, BK=32, split-K=16 (grid 4x8x16=512 WGs)
// ---------------------------------------------------------------------------
__global__ __launch_bounds__(256, 2) void gemm_ih(
    const float* __restrict__ Z, const float* __restrict__ W,
    float* __restrict__ part) {
  const int mt = blockIdx.x;  // 0..3
  const int nt = blockIdx.y;  // 0..7
  const int kz = blockIdx.z;  // 0..15
  const int k0 = kz * KRANGE_;
  __shared__ float As[32 * 132];
  __shared__ float Bs[32 * 132];
  const int tid = threadIdx.x;
  const int lrow = tid >> 3;       // 0..31
  const int kq = tid & 7;          // k-quad
  const int mi = (tid & 15) * 8;   // micro row base
  const int ni = (tid >> 4) * 8;   // micro col base

  float acc[8][8];
#pragma unroll
  for (int i = 0; i < 8; ++i)
#pragma unroll
    for (int j = 0; j < 8; ++j) acc[i][j] = 0.f;

  for (int it = 0; it < 63; ++it) {
    const int kb = k0 + it * 32;
#pragma unroll
    for (int p = 0; p < 4; ++p) {
      const int rl = lrow + p * 32;
      const int gk = kb + kq * 4;
      const bool kok = (gk + 4) <= (k0 + KRANGE_);
      const int gr = mt * 128 + rl;
      float4 va = make_float4(0.f, 0.f, 0.f, 0.f);
      if (kok && gr < R_) va = *(const float4*)(Z + (size_t)gr * K0_ + gk);
      As[(kq * 4 + 0) * 132 + rl] = va.x;
      As[(kq * 4 + 1) * 132 + rl] = va.y;
      As[(kq * 4 + 2) * 132 + rl] = va.z;
      As[(kq * 4 + 3) * 132 + rl] = va.w;
      const int gn = nt * 128 + rl;
      float4 vb = make_float4(0.f, 0.f, 0.f, 0.f);
      if (kok) vb = *(const float4*)(W + (size_t)gn * K0_ + gk);
      Bs[(kq * 4 + 0) * 132 + rl] = vb.x;
      Bs[(kq * 4 + 1) * 132 + rl] = vb.y;
      Bs[(kq * 4 + 2) * 132 + rl] = vb.z;
      Bs[(kq * 4 + 3) * 132 + rl] = vb.w;
    }
    __syncthreads();
#pragma unroll 4
    for (int kk = 0; kk < 32; ++kk) {
      float avv[8], bvv[8];
      *(float4*)&avv[0] = *(const float4*)&As[kk * 132 + mi];
      *(float4*)&avv[4] = *(const float4*)&As[kk * 132 + mi + 4];
      *(float4*)&bvv[0] = *(const float4*)&Bs[kk * 132 + ni];
      *(float4*)&bvv[4] = *(const float4*)&Bs[kk * 132 + ni + 4];
#pragma unroll
      for (int i = 0; i < 8; ++i)
#pragma unroll
        for (int j = 0; j < 8; ++j) acc[i][j] += avv[i] * bvv[j];
    }
    __syncthreads();
  }
#pragma unroll
  for (int i = 0; i < 8; ++i) {
    const int gr = mt * 128 + mi + i;
    if (gr < R_) {
#pragma unroll
      for (int j = 0; j < 8; ++j)
        part[((size_t)kz * R_ + gr) * NG_ + nt * 128 + ni + j] = acc[i][j];
    }
  }
}

// ---------------------------------------------------------------------------
// Kernel 3: reduce split-K partials + input-side biases -> G0[400][1024]
// ---------------------------------------------------------------------------
__global__ __launch_bounds__(256) void reduce_kernel(
    const float* __restrict__ part, const float* __restrict__ bih0,
    const float* __restrict__ bhh0, float* __restrict__ G0) {
  const int idx = blockIdx.x * 256 + threadIdx.x;
  if (idx >= R_ * NG_) return;
  const int n = idx & (NG_ - 1);
  float s = bih0[n] + bhh0[n];
#pragma unroll
  for (int ks = 0; ks < KS_; ++ks) s += part[(size_t)ks * R_ * NG_ + idx];
  G0[idx] = s;
}

// ---------------------------------------------------------------------------
// Kernel 4: persistent 2-layer LSTM recurrence. 64 WGs (all co-resident):
// WGs 0..31 = layer0 (j-slice of 8 across 4 gates), 32..63 = layer1,
// staggered one step. Cross-WG handoff via agent-scope atomics.
// ---------------------------------------------------------------------------
#define WSTR 260  // LDS W row stride (floats), 16B-aligned

__device__ __forceinline__ void wait_cnt(unsigned* p, unsigned want) {
  unsigned tries = 0;
  while (__hip_atomic_load(p, __ATOMIC_ACQUIRE, __HIP_MEMORY_SCOPE_AGENT) < want) {
    __builtin_amdgcn_s_sleep(2);
    if (++tries > (1u << 24)) break;  // bail instead of hanging
  }
}

__global__ __launch_bounds__(256, 1) void recur_kernel(
    const float* __restrict__ G0, const float* __restrict__ Whh0,
    const float* __restrict__ Wih1, const float* __restrict__ Whh1,
    const float* __restrict__ bih1, const float* __restrict__ bhh1,
    float* __restrict__ h1b, float* __restrict__ h2b,
    unsigned* __restrict__ cnt0, unsigned* __restrict__ cnt1) {
  const int wg = blockIdx.x;
  const int tid = threadIdx.x;
  const bool is1 = wg >= 32;
  const int w = is1 ? wg - 32 : wg;
  const int jb = w * 8;
  const int m = tid >> 5;         // batch 0..7
  const int q = (tid >> 3) & 3;   // gate 0..3 (i,f,g,o)
  const int jj = tid & 7;
  const int n = q * 256 + jb + jj;

  __shared__ float Wa[32 * WSTR];
  __shared__ float Wb[32 * WSTR];
  __shared__ float h1s[8 * 256];
  __shared__ float h2s[8 * 256];
  __shared__ float gs[4 * 64];
  __shared__ float cs[64];

  // stage this WG's weight rows once (row ri = q*8+jj <-> global q*256+jb+jj)
  for (int idx = tid; idx < 32 * 256; idx += 256) {
    const int ri = idx >> 8, k = idx & 255;
    const int gr = (ri >> 3) * 256 + jb + (ri & 7);
    if (!is1) {
      Wa[ri * WSTR + k] = Whh0[(size_t)gr * 256 + k];
    } else {
      Wa[ri * WSTR + k] = Wih1[(size_t)gr * 256 + k];
      Wb[ri * WSTR + k] = Whh1[(size_t)gr * 256 + k];
    }
  }
  if (tid < 64) cs[tid] = 0.f;
  const float bias1 = is1 ? (bih1[n] + bhh1[n]) : 0.f;
  __syncthreads();

  const float* warow = &Wa[(q * 8 + jj) * WSTR];
  const float* wbrow = &Wb[(q * 8 + jj) * WSTR];

  for (int t = 0; t < T_; ++t) {
    // ---- acquire inputs ----
    if (tid == 0) {
      if (!is1) {
        if (t > 0) wait_cnt(&cnt0[t - 1], 32);
      } else {
        wait_cnt(&cnt0[t], 32);
        if (t > 0) wait_cnt(&cnt1[t - 1], 32);
      }
    }
    __syncthreads();
    // ---- stage h state (agent-scope relaxed atomics: bypass stale caches) ----
    if (!is1) {
      for (int i = tid; i < 2048; i += 256)
        h1s[i] = __hip_atomic_load(h1b + (size_t)t * 2048 + i, __ATOMIC_RELAXED,
                                   __HIP_MEMORY_SCOPE_AGENT);
    } else {
      for (int i = tid; i < 2048; i += 256) {
        h1s[i] = __hip_atomic_load(h1b + (size_t)(t + 1) * 2048 + i,
                                   __ATOMIC_RELAXED, __HIP_MEMORY_SCOPE_AGENT);
        h2s[i] = __hip_atomic_load(h2b + (size_t)t * 2048 + i, __ATOMIC_RELAXED,
                                   __HIP_MEMORY_SCOPE_AGENT);
      }
    }
    __syncthreads();

    // ---- gate dot products ----
    float acc;
    if (!is1) {
      acc = G0[(size_t)(m * T_ + t) * NG_ + n];
      float a0 = 0.f, a1 = 0.f, a2 = 0.f, a3 = 0.f;
      const float* h = &h1s[m * 256];
#pragma unroll 8
      for (int k = 0; k < 256; k += 4) {
        float4 wv = *(const float4*)&warow[k];
        float4 hv = *(const float4*)&h[k];
        a0 += wv.x * hv.x; a1 += wv.y * hv.y;
        a2 += wv.z * hv.z; a3 += wv.w * hv.w;
      }
      acc += (a0 + a1) + (a2 + a3);
    } else {
      acc = bias1;
      float a0 = 0.f, a1 = 0.f, a2 = 0.f, a3 = 0.f;
      const float* h1p = &h1s[m * 256];
      const float* h2p = &h2s[m * 256];
#pragma unroll 8
      for (int k = 0; k < 256; k += 4) {
        float4 wv = *(const float4*)&warow[k];
        float4 hv = *(const float4*)&h1p[k];
        a0 += wv.x * hv.x; a1 += wv.y * hv.y;
        a2 += wv.z * hv.z; a3 += wv.w * hv.w;
        float4 wv2 = *(const float4*)&wbrow[k];
        float4 hv2 = *(const float4*)&h2p[k];
        a0 += wv2.x * hv2.x; a1 += wv2.y * hv2.y;
        a2 += wv2.z * hv2.z; a3 += wv2.w * hv2.w;
      }
      acc += (a0 + a1) + (a2 + a3);
    }
    gs[q * 64 + m * 8 + jj] = acc;
    __syncthreads();

    // ---- pointwise LSTM cell update (64 threads own (m,j) pairs) ----
    if (tid < 64) {
      const int mm = tid >> 3, j2 = tid & 7;
      const float gi = gs[tid];
      const float gf = gs[64 + tid];
      const float gg = gs[128 + tid];
      const float go = gs[192 + tid];
      float c = sigm(gf) * cs[tid] + sigm(gi) * tanhf(gg);
      cs[tid] = c;
      const float h = sigm(go) * tanhf(c);
      float* ob = is1 ? h2b : h1b;
      __hip_atomic_store(ob + (size_t)(t + 1) * 2048 + mm * 256 + jb + j2, h,
                         __ATOMIC_RELAXED, __HIP_MEMORY_SCOPE_AGENT);
    }
    __syncthreads();
    // ---- release ----
    if (tid == 0) {
      __threadfence();
      __hip_atomic_fetch_add(is1 ? &cnt1[t] : &cnt0[t], 1u, __ATOMIC_RELEASE,
                             __HIP_MEMORY_SCOPE_AGENT);
    }
  }
}

// ---------------------------------------------------------------------------
// Kernel 5: FC head  out[8][20000] = tanh(h2[49]) @ fcW^T + fcb
// ---------------------------------------------------------------------------
__global__ __launch_bounds__(256) void fc_kernel(
    const float* __restrict__ h2last, const float* __restrict__ fcW,
    const float* __restrict__ fcb, float* __restrict__ out) {
  __shared__ float tl[2048];
  const int tid = threadIdx.x;
  for (int i = tid; i < 2048; i += 256) tl[i] = tanhf(h2last[i]);
  __syncthreads();
  const int nidx = blockIdx.x * 256 + tid;
  if (nidx >= S_ * N_ * F_) return;
  float accv[8];
#pragma unroll
  for (int m2 = 0; m2 < 8; ++m2) accv[m2] = 0.f;
  const float* wr = fcW + (size_t)nidx * 256;
  for (int k = 0; k < 256; k += 4) {
    float4 w4 = *(const float4*)(wr + k);
#pragma unroll
    for (int m2 = 0; m2 < 8; ++m2) {
      float4 t4 = *(const float4*)&tl[m2 * 256 + k];
      accv[m2] += w4.x * t4.x + w4.y * t4.y + w4.z * t4.z + w4.w * t4.w;
    }
  }
  const float bv = fcb[nidx];
#pragma unroll
  for (int m2 = 0; m2 < 8; ++m2) out[(size_t)m2 * (S_ * N_ * F_) + nidx] = accv[m2] + bv;
}

// ---------------------------------------------------------------------------
// Launch: workspace layout (floats):
//   Z     @ 0          : 400*32000      = 12,800,000
//   part  @ 12,800,000 : 16*400*1024    =  6,553,600
//   G0    @ 19,353,600 : 400*1024       =    409,600
//   h1b   @ 19,763,200 : 51*2048        =    104,448
//   h2b   @ 19,867,648 : 51*2048        =    104,448
//   flags @ 19,972,096 : 128 uint
// total ~79.9 MB of d_ws
// ---------------------------------------------------------------------------
extern "C" void kernel_launch(void* const* d_in, const int* in_sizes, int n_in,
                              void* d_out, int out_size, void* d_ws, size_t ws_size,
                              hipStream_t stream) {
  const float* x    = (const float*)d_in[0];
  const int*   ei   = (const int*)d_in[1];
  const float* ew   = (const float*)d_in[2];
  const float* Wg   = (const float*)d_in[3];
  const float* bg   = (const float*)d_in[4];
  const float* Wih0 = (const float*)d_in[5];
  const float* Whh0 = (const float*)d_in[6];
  const float* bih0 = (const float*)d_in[7];
  const float* bhh0 = (const float*)d_in[8];
  const float* Wih1 = (const float*)d_in[9];
  const float* Whh1 = (const float*)d_in[10];
  const float* bih1 = (const float*)d_in[11];
  const float* bhh1 = (const float*)d_in[12];
  const float* fcW  = (const float*)d_in[13];
  const float* fcb  = (const float*)d_in[14];
  float* out = (float*)d_out;
  float* ws = (float*)d_ws;

  float* Z    = ws;
  float* part = ws + 12800000;
  float* G0   = ws + 19353600;
  float* h1b  = ws + 19763200;
  float* h2b  = ws + 19867648;
  unsigned* cnt0 = (unsigned*)(ws + 19972096);
  unsigned* cnt1 = cnt0 + 64;

  // zero h-state slot0 + flags every call (ws is re-poisoned by harness)
  hipMemsetAsync(h1b, 0, (size_t)(104448 * 2 + 128) * sizeof(float), stream);

  gcn_kernel<<<R_, 256, 0, stream>>>(x, ei, ew, Wg, bg, Z);
  gemm_ih<<<dim3(4, 8, KS_), 256, 0, stream>>>(Z, Wih0, part);
  reduce_kernel<<<(R_ * NG_ + 255) / 256, 256, 0, stream>>>(part, bih0, bhh0, G0);
  recur_kernel<<<64, 256, 0, stream>>>(G0, Whh0, Wih1, Whh1, bih1, bhh1, h1b,
                                       h2b, cnt0, cnt1);
  fc_kernel<<<(S_ * N_ * F_ + 255) / 256, 256, 0, stream>>>(h2b + 50 * 2048,
                                                            fcW, fcb, out);
}

// Round 2
// 3920.209 us; speedup vs baseline: 1.0445x; 1.0445x over previous
//
#include <hip/hip_runtime.h>
#include <math.h>

// Problem constants
#define B_ 8
#define T_ 50
#define N_ 1000
#define F_ 4
#define G_ 32
#define H_ 256
#define E_ 32000
#define S_ 5
#define R_ 400        // B*T
#define K0_ 32000     // N*G (LSTM0 input size)
#define NG_ 1024      // 4*H
#define KS_ 16        // split-K factor for big GEMM
#define KRANGE_ 2000  // K0_/KS_

static __device__ __forceinline__ float sigm(float x) { return 1.0f / (1.0f + expf(-x)); }

// ---------------------------------------------------------------------------
// Kernel 1: GCN. 2 WGs per (b,t), split by g-half (16 channels each).
// LDS: x 16 KB + agg 64 KB = 80 KB -> 2 WGs/CU; 1024 thr -> 32 waves/CU.
// Atomic index XOR-swizzled so same-g' lanes with different dst hit
// different banks (>=2-way only, free per m136).
// ---------------------------------------------------------------------------
__global__ __launch_bounds__(1024, 8) void gcn_kernel(
    const float* __restrict__ x, const int* __restrict__ ei,
    const float* __restrict__ ew, const float* __restrict__ Wg,
    const float* __restrict__ bg, float* __restrict__ Z) {
  __shared__ float4 xs4[N_];        // 16 KB  (x[n][0..3])
  __shared__ float agg[N_ * 16];    // 64 KB  (this WG's g-half)
  const int r = blockIdx.x >> 1;
  const int gh = blockIdx.x & 1;    // g-half: channels gh*16 .. gh*16+15
  const int tid = threadIdx.x;

  // stage x row-block (coalesced float4)
  const float4* xg = (const float4*)(x + (size_t)r * N_ * F_);
  for (int i = tid; i < N_; i += 1024) xs4[i] = xg[i];
  // zero agg
  float4* av = (float4*)agg;
  for (int i = tid; i < N_ * 4; i += 1024) av[i] = make_float4(0.f, 0.f, 0.f, 0.f);

  const int g = tid & 15;           // g' within half
  const int gg = gh * 16 + g;       // global channel
  const float w0 = Wg[0 * G_ + gg], w1 = Wg[1 * G_ + gg];
  const float w2 = Wg[2 * G_ + gg], w3 = Wg[3 * G_ + gg];
  __syncthreads();

  const int* src = ei + (size_t)r * 2 * E_;
  const int* dst = src + E_;
  const float* wp = ew + (size_t)r * E_;

  // wave = 4 edge-slots x 16 channels; 2-edge batch, 250 edge-visits/thread
  const int es = tid >> 4;          // 0..63
  for (int e = es; e < E_; e += 128) {
    int s0 = src[e], s1 = src[e + 64];
    int d0 = dst[e], d1 = dst[e + 64];
    float we0 = wp[e], we1 = wp[e + 64];
    float4 x0 = xs4[s0], x1 = xs4[s1];
    float m0 = we0 * (x0.x * w0 + x0.y * w1 + x0.z * w2 + x0.w * w3);
    float m1 = we1 * (x1.x * w0 + x1.y * w1 + x1.z * w2 + x1.w * w3);
    atomicAdd(&agg[(d0 << 4) | (g ^ ((d0 & 3) << 2))], m0);
    atomicAdd(&agg[(d1 << 4) | (g ^ ((d1 & 3) << 2))], m1);
  }
  __syncthreads();

  // z = tanh(agg + b_gcn), k = n*32 + gh*16 + g'
  const float bgv = bg[gg];         // each thread keeps fixed g' = tid&15
  float* Zr = Z + (size_t)r * K0_;
  for (int i = tid; i < N_ * 16; i += 1024) {
    const int n = i >> 4, gp = i & 15;  // gp == tid&15 (1024 % 16 == 0)
    const float v = agg[(n << 4) | (gp ^ ((n & 3) << 2))];
    Zr[n * 32 + gh * 16 + gp] = tanhf(v + bgv);
  }
}

// ---------------------------------------------------------------------------
// Kernel 2: big input GEMM  part[kz] += Z(400x32000) @ Wih0^T(32000x1024)
// fp32, 128x128 tile, 8x8 microtile, BK=32, split-K=16 (grid 4x8x16=512 WGs)
// ---------------------------------------------------------------------------
__global__ __launch_bounds__(256, 2) void gemm_ih(
    const float* __restrict__ Z, const float* __restrict__ W,
    float* __restrict__ part) {
  const int mt = blockIdx.x;  // 0..3
  const int nt = blockIdx.y;  // 0..7
  const int kz = blockIdx.z;  // 0..15
  const int k0 = kz * KRANGE_;
  __shared__ float As[32 * 132];
  __shared__ float Bs[32 * 132];
  const int tid = threadIdx.x;
  const int lrow = tid >> 3;       // 0..31
  const int kq = tid & 7;          // k-quad
  const int mi = (tid & 15) * 8;   // micro row base
  const int ni = (tid >> 4) * 8;   // micro col base

  float acc[8][8];
#pragma unroll
  for (int i = 0; i < 8; ++i)
#pragma unroll
    for (int j = 0; j < 8; ++j) acc[i][j] = 0.f;

  for (int it = 0; it < 63; ++it) {
    const int kb = k0 + it * 32;
#pragma unroll
    for (int p = 0; p < 4; ++p) {
      const int rl = lrow + p * 32;
      const int gk = kb + kq * 4;
      const bool kok = (gk + 4) <= (k0 + KRANGE_);
      const int gr = mt * 128 + rl;
      float4 va = make_float4(0.f, 0.f, 0.f, 0.f);
      if (kok && gr < R_) va = *(const float4*)(Z + (size_t)gr * K0_ + gk);
      As[(kq * 4 + 0) * 132 + rl] = va.x;
      As[(kq * 4 + 1) * 132 + rl] = va.y;
      As[(kq * 4 + 2) * 132 + rl] = va.z;
      As[(kq * 4 + 3) * 132 + rl] = va.w;
      const int gn = nt * 128 + rl;
      float4 vb = make_float4(0.f, 0.f, 0.f, 0.f);
      if (kok) vb = *(const float4*)(W + (size_t)gn * K0_ + gk);
      Bs[(kq * 4 + 0) * 132 + rl] = vb.x;
      Bs[(kq * 4 + 1) * 132 + rl] = vb.y;
      Bs[(kq * 4 + 2) * 132 + rl] = vb.z;
      Bs[(kq * 4 + 3) * 132 + rl] = vb.w;
    }
    __syncthreads();
#pragma unroll 4
    for (int kk = 0; kk < 32; ++kk) {
      float avv[8], bvv[8];
      *(float4*)&avv[0] = *(const float4*)&As[kk * 132 + mi];
      *(float4*)&avv[4] = *(const float4*)&As[kk * 132 + mi + 4];
      *(float4*)&bvv[0] = *(const float4*)&Bs[kk * 132 + ni];
      *(float4*)&bvv[4] = *(const float4*)&Bs[kk * 132 + ni + 4];
#pragma unroll
      for (int i = 0; i < 8; ++i)
#pragma unroll
        for (int j = 0; j < 8; ++j) acc[i][j] += avv[i] * bvv[j];
    }
    __syncthreads();
  }
#pragma unroll
  for (int i = 0; i < 8; ++i) {
    const int gr = mt * 128 + mi + i;
    if (gr < R_) {
#pragma unroll
      for (int j = 0; j < 8; ++j)
        part[((size_t)kz * R_ + gr) * NG_ + nt * 128 + ni + j] = acc[i][j];
    }
  }
}

// ---------------------------------------------------------------------------
// Kernel 3: reduce split-K partials + input-side biases -> G0[400][1024]
// ---------------------------------------------------------------------------
__global__ __launch_bounds__(256) void reduce_kernel(
    const float* __restrict__ part, const float* __restrict__ bih0,
    const float* __restrict__ bhh0, float* __restrict__ G0) {
  const int idx = blockIdx.x * 256 + threadIdx.x;
  if (idx >= R_ * NG_) return;
  const int n = idx & (NG_ - 1);
  float s = bih0[n] + bhh0[n];
#pragma unroll
  for (int ks = 0; ks < KS_; ++ks) s += part[(size_t)ks * R_ * NG_ + idx];
  G0[idx] = s;
}

// ---------------------------------------------------------------------------
// Kernel 4: persistent 2-layer LSTM recurrence. 64 WGs (all co-resident):
// WGs 0..31 = layer0 (j-slice of 8 across 4 gates), 32..63 = layer1,
// staggered one step. Cross-WG handoff via agent-scope atomics.
// ---------------------------------------------------------------------------
#define WSTR 260  // LDS W row stride (floats), 16B-aligned

__device__ __forceinline__ void wait_cnt(unsigned* p, unsigned want) {
  unsigned tries = 0;
  while (__hip_atomic_load(p, __ATOMIC_ACQUIRE, __HIP_MEMORY_SCOPE_AGENT) < want) {
    __builtin_amdgcn_s_sleep(2);
    if (++tries > (1u << 24)) break;  // bail instead of hanging
  }
}

__global__ __launch_bounds__(256, 1) void recur_kernel(
    const float* __restrict__ G0, const float* __restrict__ Whh0,
    const float* __restrict__ Wih1, const float* __restrict__ Whh1,
    const float* __restrict__ bih1, const float* __restrict__ bhh1,
    float* __restrict__ h1b, float* __restrict__ h2b,
    unsigned* __restrict__ cnt0, unsigned* __restrict__ cnt1) {
  const int wg = blockIdx.x;
  const int tid = threadIdx.x;
  const bool is1 = wg >= 32;
  const int w = is1 ? wg - 32 : wg;
  const int jb = w * 8;
  const int m = tid >> 5;         // batch 0..7
  const int q = (tid >> 3) & 3;   // gate 0..3 (i,f,g,o)
  const int jj = tid & 7;
  const int n = q * 256 + jb + jj;

  __shared__ float Wa[32 * WSTR];
  __shared__ float Wb[32 * WSTR];
  __shared__ float h1s[8 * 256];
  __shared__ float h2s[8 * 256];
  __shared__ float gs[4 * 64];
  __shared__ float cs[64];

  // stage this WG's weight rows once (row ri = q*8+jj <-> global q*256+jb+jj)
  for (int idx = tid; idx < 32 * 256; idx += 256) {
    const int ri = idx >> 8, k = idx & 255;
    const int gr = (ri >> 3) * 256 + jb + (ri & 7);
    if (!is1) {
      Wa[ri * WSTR + k] = Whh0[(size_t)gr * 256 + k];
    } else {
      Wa[ri * WSTR + k] = Wih1[(size_t)gr * 256 + k];
      Wb[ri * WSTR + k] = Whh1[(size_t)gr * 256 + k];
    }
  }
  if (tid < 64) cs[tid] = 0.f;
  const float bias1 = is1 ? (bih1[n] + bhh1[n]) : 0.f;
  __syncthreads();

  const float* warow = &Wa[(q * 8 + jj) * WSTR];
  const float* wbrow = &Wb[(q * 8 + jj) * WSTR];

  for (int t = 0; t < T_; ++t) {
    // ---- acquire inputs ----
    if (tid == 0) {
      if (!is1) {
        if (t > 0) wait_cnt(&cnt0[t - 1], 32);
      } else {
        wait_cnt(&cnt0[t], 32);
        if (t > 0) wait_cnt(&cnt1[t - 1], 32);
      }
    }
    __syncthreads();
    // ---- stage h state (agent-scope relaxed atomics: bypass stale caches) ----
    if (!is1) {
      for (int i = tid; i < 2048; i += 256)
        h1s[i] = __hip_atomic_load(h1b + (size_t)t * 2048 + i, __ATOMIC_RELAXED,
                                   __HIP_MEMORY_SCOPE_AGENT);
    } else {
      for (int i = tid; i < 2048; i += 256) {
        h1s[i] = __hip_atomic_load(h1b + (size_t)(t + 1) * 2048 + i,
                                   __ATOMIC_RELAXED, __HIP_MEMORY_SCOPE_AGENT);
        h2s[i] = __hip_atomic_load(h2b + (size_t)t * 2048 + i, __ATOMIC_RELAXED,
                                   __HIP_MEMORY_SCOPE_AGENT);
      }
    }
    __syncthreads();

    // ---- gate dot products ----
    float acc;
    if (!is1) {
      acc = G0[(size_t)(m * T_ + t) * NG_ + n];
      float a0 = 0.f, a1 = 0.f, a2 = 0.f, a3 = 0.f;
      const float* h = &h1s[m * 256];
#pragma unroll 8
      for (int k = 0; k < 256; k += 4) {
        float4 wv = *(const float4*)&warow[k];
        float4 hv = *(const float4*)&h[k];
        a0 += wv.x * hv.x; a1 += wv.y * hv.y;
        a2 += wv.z * hv.z; a3 += wv.w * hv.w;
      }
      acc += (a0 + a1) + (a2 + a3);
    } else {
      acc = bias1;
      float a0 = 0.f, a1 = 0.f, a2 = 0.f, a3 = 0.f;
      const float* h1p = &h1s[m * 256];
      const float* h2p = &h2s[m * 256];
#pragma unroll 8
      for (int k = 0; k < 256; k += 4) {
        float4 wv = *(const float4*)&warow[k];
        float4 hv = *(const float4*)&h1p[k];
        a0 += wv.x * hv.x; a1 += wv.y * hv.y;
        a2 += wv.z * hv.z; a3 += wv.w * hv.w;
        float4 wv2 = *(const float4*)&wbrow[k];
        float4 hv2 = *(const float4*)&h2p[k];
        a0 += wv2.x * hv2.x; a1 += wv2.y * hv2.y;
        a2 += wv2.z * hv2.z; a3 += wv2.w * hv2.w;
      }
      acc += (a0 + a1) + (a2 + a3);
    }
    gs[q * 64 + m * 8 + jj] = acc;
    __syncthreads();

    // ---- pointwise LSTM cell update (64 threads own (m,j) pairs) ----
    if (tid < 64) {
      const int mm = tid >> 3, j2 = tid & 7;
      const float gi = gs[tid];
      const float gf = gs[64 + tid];
      const float gg = gs[128 + tid];
      const float go = gs[192 + tid];
      float c = sigm(gf) * cs[tid] + sigm(gi) * tanhf(gg);
      cs[tid] = c;
      const float h = sigm(go) * tanhf(c);
      float* ob = is1 ? h2b : h1b;
      __hip_atomic_store(ob + (size_t)(t + 1) * 2048 + mm * 256 + jb + j2, h,
                         __ATOMIC_RELAXED, __HIP_MEMORY_SCOPE_AGENT);
    }
    __syncthreads();
    // ---- release ----
    if (tid == 0) {
      __threadfence();
      __hip_atomic_fetch_add(is1 ? &cnt1[t] : &cnt0[t], 1u, __ATOMIC_RELEASE,
                             __HIP_MEMORY_SCOPE_AGENT);
    }
  }
}

// ---------------------------------------------------------------------------
// Kernel 5: FC head  out[8][20000] = tanh(h2[49]) @ fcW^T + fcb
// ---------------------------------------------------------------------------
__global__ __launch_bounds__(256) void fc_kernel(
    const float* __restrict__ h2last, const float* __restrict__ fcW,
    const float* __restrict__ fcb, float* __restrict__ out) {
  __shared__ float tl[2048];
  const int tid = threadIdx.x;
  for (int i = tid; i < 2048; i += 256) tl[i] = tanhf(h2last[i]);
  __syncthreads();
  const int nidx = blockIdx.x * 256 + tid;
  if (nidx >= S_ * N_ * F_) return;
  float accv[8];
#pragma unroll
  for (int m2 = 0; m2 < 8; ++m2) accv[m2] = 0.f;
  const float* wr = fcW + (size_t)nidx * 256;
  for (int k = 0; k < 256; k += 4) {
    float4 w4 = *(const float4*)(wr + k);
#pragma unroll
    for (int m2 = 0; m2 < 8; ++m2) {
      float4 t4 = *(const float4*)&tl[m2 * 256 + k];
      accv[m2] += w4.x * t4.x + w4.y * t4.y + w4.z * t4.z + w4.w * t4.w;
    }
  }
  const float bv = fcb[nidx];
#pragma unroll
  for (int m2 = 0; m2 < 8; ++m2) out[(size_t)m2 * (S_ * N_ * F_) + nidx] = accv[m2] + bv;
}

// ---------------------------------------------------------------------------
// Launch: workspace layout (floats):
//   Z     @ 0          : 400*32000      = 12,800,000
//   part  @ 12,800,000 : 16*400*1024    =  6,553,600
//   G0    @ 19,353,600 : 400*1024       =    409,600
//   h1b   @ 19,763,200 : 51*2048        =    104,448
//   h2b   @ 19,867,648 : 51*2048        =    104,448
//   flags @ 19,972,096 : 128 uint
// total ~79.9 MB of d_ws
// ---------------------------------------------------------------------------
extern "C" void kernel_launch(void* const* d_in, const int* in_sizes, int n_in,
                              void* d_out, int out_size, void* d_ws, size_t ws_size,
                              hipStream_t stream) {
  const float* x    = (const float*)d_in[0];
  const int*   ei   = (const int*)d_in[1];
  const float* ew   = (const float*)d_in[2];
  const float* Wg   = (const float*)d_in[3];
  const float* bg   = (const float*)d_in[4];
  const float* Wih0 = (const float*)d_in[5];
  const float* Whh0 = (const float*)d_in[6];
  const float* bih0 = (const float*)d_in[7];
  const float* bhh0 = (const float*)d_in[8];
  const float* Wih1 = (const float*)d_in[9];
  const float* Whh1 = (const float*)d_in[10];
  const float* bih1 = (const float*)d_in[11];
  const float* bhh1 = (const float*)d_in[12];
  const float* fcW  = (const float*)d_in[13];
  const float* fcb  = (const float*)d_in[14];
  float* out = (float*)d_out;
  float* ws = (float*)d_ws;

  float* Z    = ws;
  float* part = ws + 12800000;
  float* G0   = ws + 19353600;
  float* h1b  = ws + 19763200;
  float* h2b  = ws + 19867648;
  unsigned* cnt0 = (unsigned*)(ws + 19972096);
  unsigned* cnt1 = cnt0 + 64;

  // zero h-state slot0 + flags every call (ws is re-poisoned by harness)
  hipMemsetAsync(h1b, 0, (size_t)(104448 * 2 + 128) * sizeof(float), stream);

  gcn_kernel<<<R_ * 2, 1024, 0, stream>>>(x, ei, ew, Wg, bg, Z);
  gemm_ih<<<dim3(4, 8, KS_), 256, 0, stream>>>(Z, Wih0, part);
  reduce_kernel<<<(R_ * NG_ + 255) / 256, 256, 0, stream>>>(part, bih0, bhh0, G0);
  recur_kernel<<<64, 256, 0, stream>>>(G0, Whh0, Wih1, Whh1, bih1, bhh1, h1b,
                                       h2b, cnt0, cnt1);
  fc_kernel<<<(S_ * N_ * F_ + 255) / 256, 256, 0, stream>>>(h2b + 50 * 2048,
                                                            fcW, fcb, out);
}

// Round 3
// 3916.143 us; speedup vs baseline: 1.0456x; 1.0010x over previous
//
#include <hip/hip_runtime.h>
#include <math.h>

// Problem constants
#define B_ 8
#define T_ 50
#define N_ 1000
#define F_ 4
#define G_ 32
#define H_ 256
#define E_ 32000
#define S_ 5
#define R_ 400        // B*T
#define K0_ 32000     // N*G (LSTM0 input size)
#define NG_ 1024      // 4*H
#define KS_ 16        // split-K factor for big GEMM
#define KRANGE_ 2000  // K0_/KS_

static __device__ __forceinline__ float sigm(float x) { return 1.0f / (1.0f + expf(-x)); }

// ---------------------------------------------------------------------------
// Kernel 1: GCN. 2 WGs per (b,t), split by g-half (16 channels each).
// LDS: x 16 KB + agg 64 KB = 80 KB -> 2 WGs/CU; 1024 thr -> 32 waves/CU.
// R2 fix: unsafeAtomicAdd -> native ds_add_f32 (atomicAdd(float*) on LDS
// lowers to a ds_read+ds_cmpst CAS LOOP without unsafe-fp-atomics -> the
// serial chain that made R1/R2 latency-bound at 5% VALU).
// ---------------------------------------------------------------------------
__global__ __launch_bounds__(1024, 8) void gcn_kernel(
    const float* __restrict__ x, const int* __restrict__ ei,
    const float* __restrict__ ew, const float* __restrict__ Wg,
    const float* __restrict__ bg, float* __restrict__ Z) {
  __shared__ float4 xs4[N_];        // 16 KB  (x[n][0..3])
  __shared__ float agg[N_ * 16];    // 64 KB  (this WG's g-half)
  const int r = blockIdx.x >> 1;
  const int gh = blockIdx.x & 1;    // g-half: channels gh*16 .. gh*16+15
  const int tid = threadIdx.x;

  // stage x row-block (coalesced float4)
  const float4* xg = (const float4*)(x + (size_t)r * N_ * F_);
  for (int i = tid; i < N_; i += 1024) xs4[i] = xg[i];
  // zero agg
  float4* av = (float4*)agg;
  for (int i = tid; i < N_ * 4; i += 1024) av[i] = make_float4(0.f, 0.f, 0.f, 0.f);

  const int g = tid & 15;           // g' within half
  const int gg = gh * 16 + g;       // global channel
  const float w0 = Wg[0 * G_ + gg], w1 = Wg[1 * G_ + gg];
  const float w2 = Wg[2 * G_ + gg], w3 = Wg[3 * G_ + gg];
  __syncthreads();

  const int* src = ei + (size_t)r * 2 * E_;
  const int* dst = src + E_;
  const float* wp = ew + (size_t)r * E_;

  // wave = 4 edge-slots x 16 channels; 2-edge batch, 250 edge-visits/thread
  const int es = tid >> 4;          // 0..63
  for (int e = es; e < E_; e += 128) {
    int s0 = src[e], s1 = src[e + 64];
    int d0 = dst[e], d1 = dst[e + 64];
    float we0 = wp[e], we1 = wp[e + 64];
    float4 x0 = xs4[s0], x1 = xs4[s1];
    float m0 = we0 * (x0.x * w0 + x0.y * w1 + x0.z * w2 + x0.w * w3);
    float m1 = we1 * (x1.x * w0 + x1.y * w1 + x1.z * w2 + x1.w * w3);
    unsafeAtomicAdd(&agg[(d0 << 4) | (g ^ ((d0 & 3) << 2))], m0);
    unsafeAtomicAdd(&agg[(d1 << 4) | (g ^ ((d1 & 3) << 2))], m1);
  }
  __syncthreads();

  // z = tanh(agg + b_gcn), k = n*32 + gh*16 + g'
  const float bgv = bg[gg];         // each thread keeps fixed g' = tid&15
  float* Zr = Z + (size_t)r * K0_;
  for (int i = tid; i < N_ * 16; i += 1024) {
    const int n = i >> 4, gp = i & 15;  // gp == tid&15 (1024 % 16 == 0)
    const float v = agg[(n << 4) | (gp ^ ((n & 3) << 2))];
    Zr[n * 32 + gh * 16 + gp] = tanhf(v + bgv);
  }
}

// ---------------------------------------------------------------------------
// Kernel 2: big input GEMM  part[kz] += Z(400x32000) @ Wih0^T(32000x1024)
// fp32, 128x128 tile, 8x8 microtile, BK=32, split-K=16 (grid 4x8x16=512 WGs)
// ---------------------------------------------------------------------------
__global__ __launch_bounds__(256, 2) void gemm_ih(
    const float* __restrict__ Z, const float* __restrict__ W,
    float* __restrict__ part) {
  const int mt = blockIdx.x;  // 0..3
  const int nt = blockIdx.y;  // 0..7
  const int kz = blockIdx.z;  // 0..15
  const int k0 = kz * KRANGE_;
  __shared__ float As[32 * 132];
  __shared__ float Bs[32 * 132];
  const int tid = threadIdx.x;
  const int lrow = tid >> 3;       // 0..31
  const int kq = tid & 7;          // k-quad
  const int mi = (tid & 15) * 8;   // micro row base
  const int ni = (tid >> 4) * 8;   // micro col base

  float acc[8][8];
#pragma unroll
  for (int i = 0; i < 8; ++i)
#pragma unroll
    for (int j = 0; j < 8; ++j) acc[i][j] = 0.f;

  for (int it = 0; it < 63; ++it) {
    const int kb = k0 + it * 32;
#pragma unroll
    for (int p = 0; p < 4; ++p) {
      const int rl = lrow + p * 32;
      const int gk = kb + kq * 4;
      const bool kok = (gk + 4) <= (k0 + KRANGE_);
      const int gr = mt * 128 + rl;
      float4 va = make_float4(0.f, 0.f, 0.f, 0.f);
      if (kok && gr < R_) va = *(const float4*)(Z + (size_t)gr * K0_ + gk);
      As[(kq * 4 + 0) * 132 + rl] = va.x;
      As[(kq * 4 + 1) * 132 + rl] = va.y;
      As[(kq * 4 + 2) * 132 + rl] = va.z;
      As[(kq * 4 + 3) * 132 + rl] = va.w;
      const int gn = nt * 128 + rl;
      float4 vb = make_float4(0.f, 0.f, 0.f, 0.f);
      if (kok) vb = *(const float4*)(W + (size_t)gn * K0_ + gk);
      Bs[(kq * 4 + 0) * 132 + rl] = vb.x;
      Bs[(kq * 4 + 1) * 132 + rl] = vb.y;
      Bs[(kq * 4 + 2) * 132 + rl] = vb.z;
      Bs[(kq * 4 + 3) * 132 + rl] = vb.w;
    }
    __syncthreads();
#pragma unroll 4
    for (int kk = 0; kk < 32; ++kk) {
      float avv[8], bvv[8];
      *(float4*)&avv[0] = *(const float4*)&As[kk * 132 + mi];
      *(float4*)&avv[4] = *(const float4*)&As[kk * 132 + mi + 4];
      *(float4*)&bvv[0] = *(const float4*)&Bs[kk * 132 + ni];
      *(float4*)&bvv[4] = *(const float4*)&Bs[kk * 132 + ni + 4];
#pragma unroll
      for (int i = 0; i < 8; ++i)
#pragma unroll
        for (int j = 0; j < 8; ++j) acc[i][j] += avv[i] * bvv[j];
    }
    __syncthreads();
  }
#pragma unroll
  for (int i = 0; i < 8; ++i) {
    const int gr = mt * 128 + mi + i;
    if (gr < R_) {
#pragma unroll
      for (int j = 0; j < 8; ++j)
        part[((size_t)kz * R_ + gr) * NG_ + nt * 128 + ni + j] = acc[i][j];
    }
  }
}

// ---------------------------------------------------------------------------
// Kernel 3: reduce split-K partials + input-side biases -> G0[400][1024]
// ---------------------------------------------------------------------------
__global__ __launch_bounds__(256) void reduce_kernel(
    const float* __restrict__ part, const float* __restrict__ bih0,
    const float* __restrict__ bhh0, float* __restrict__ G0) {
  const int idx = blockIdx.x * 256 + threadIdx.x;
  if (idx >= R_ * NG_) return;
  const int n = idx & (NG_ - 1);
  float s = bih0[n] + bhh0[n];
#pragma unroll
  for (int ks = 0; ks < KS_; ++ks) s += part[(size_t)ks * R_ * NG_ + idx];
  G0[idx] = s;
}

// ---------------------------------------------------------------------------
// Kernel 4: persistent 2-layer LSTM recurrence. 64 WGs (all co-resident):
// WGs 0..31 = layer0 (j-slice of 8 across 4 gates), 32..63 = layer1,
// staggered one step. Cross-WG handoff via agent-scope atomics.
// ---------------------------------------------------------------------------
#define WSTR 260  // LDS W row stride (floats), 16B-aligned

__device__ __forceinline__ void wait_cnt(unsigned* p, unsigned want) {
  unsigned tries = 0;
  while (__hip_atomic_load(p, __ATOMIC_ACQUIRE, __HIP_MEMORY_SCOPE_AGENT) < want) {
    __builtin_amdgcn_s_sleep(2);
    if (++tries > (1u << 24)) break;  // bail instead of hanging
  }
}

__global__ __launch_bounds__(256, 1) void recur_kernel(
    const float* __restrict__ G0, const float* __restrict__ Whh0,
    const float* __restrict__ Wih1, const float* __restrict__ Whh1,
    const float* __restrict__ bih1, const float* __restrict__ bhh1,
    float* __restrict__ h1b, float* __restrict__ h2b,
    unsigned* __restrict__ cnt0, unsigned* __restrict__ cnt1) {
  const int wg = blockIdx.x;
  const int tid = threadIdx.x;
  const bool is1 = wg >= 32;
  const int w = is1 ? wg - 32 : wg;
  const int jb = w * 8;
  const int m = tid >> 5;         // batch 0..7
  const int q = (tid >> 3) & 3;   // gate 0..3 (i,f,g,o)
  const int jj = tid & 7;
  const int n = q * 256 + jb + jj;

  __shared__ float Wa[32 * WSTR];
  __shared__ float Wb[32 * WSTR];
  __shared__ float h1s[8 * 256];
  __shared__ float h2s[8 * 256];
  __shared__ float gs[4 * 64];
  __shared__ float cs[64];

  // stage this WG's weight rows once (row ri = q*8+jj <-> global q*256+jb+jj)
  for (int idx = tid; idx < 32 * 256; idx += 256) {
    const int ri = idx >> 8, k = idx & 255;
    const int gr = (ri >> 3) * 256 + jb + (ri & 7);
    if (!is1) {
      Wa[ri * WSTR + k] = Whh0[(size_t)gr * 256 + k];
    } else {
      Wa[ri * WSTR + k] = Wih1[(size_t)gr * 256 + k];
      Wb[ri * WSTR + k] = Whh1[(size_t)gr * 256 + k];
    }
  }
  if (tid < 64) cs[tid] = 0.f;
  const float bias1 = is1 ? (bih1[n] + bhh1[n]) : 0.f;
  __syncthreads();

  const float* warow = &Wa[(q * 8 + jj) * WSTR];
  const float* wbrow = &Wb[(q * 8 + jj) * WSTR];

  for (int t = 0; t < T_; ++t) {
    // ---- acquire inputs ----
    if (tid == 0) {
      if (!is1) {
        if (t > 0) wait_cnt(&cnt0[t - 1], 32);
      } else {
        wait_cnt(&cnt0[t], 32);
        if (t > 0) wait_cnt(&cnt1[t - 1], 32);
      }
    }
    __syncthreads();
    // ---- stage h state (agent-scope relaxed atomics: bypass stale caches) ----
    if (!is1) {
      for (int i = tid; i < 2048; i += 256)
        h1s[i] = __hip_atomic_load(h1b + (size_t)t * 2048 + i, __ATOMIC_RELAXED,
                                   __HIP_MEMORY_SCOPE_AGENT);
    } else {
      for (int i = tid; i < 2048; i += 256) {
        h1s[i] = __hip_atomic_load(h1b + (size_t)(t + 1) * 2048 + i,
                                   __ATOMIC_RELAXED, __HIP_MEMORY_SCOPE_AGENT);
        h2s[i] = __hip_atomic_load(h2b + (size_t)t * 2048 + i, __ATOMIC_RELAXED,
                                   __HIP_MEMORY_SCOPE_AGENT);
      }
    }
    __syncthreads();

    // ---- gate dot products ----
    float acc;
    if (!is1) {
      acc = G0[(size_t)(m * T_ + t) * NG_ + n];
      float a0 = 0.f, a1 = 0.f, a2 = 0.f, a3 = 0.f;
      const float* h = &h1s[m * 256];
#pragma unroll 8
      for (int k = 0; k < 256; k += 4) {
        float4 wv = *(const float4*)&warow[k];
        float4 hv = *(const float4*)&h[k];
        a0 += wv.x * hv.x; a1 += wv.y * hv.y;
        a2 += wv.z * hv.z; a3 += wv.w * hv.w;
      }
      acc += (a0 + a1) + (a2 + a3);
    } else {
      acc = bias1;
      float a0 = 0.f, a1 = 0.f, a2 = 0.f, a3 = 0.f;
      const float* h1p = &h1s[m * 256];
      const float* h2p = &h2s[m * 256];
#pragma unroll 8
      for (int k = 0; k < 256; k += 4) {
        float4 wv = *(const float4*)&warow[k];
        float4 hv = *(const float4*)&h1p[k];
        a0 += wv.x * hv.x; a1 += wv.y * hv.y;
        a2 += wv.z * hv.z; a3 += wv.w * hv.w;
        float4 wv2 = *(const float4*)&wbrow[k];
        float4 hv2 = *(const float4*)&h2p[k];
        a0 += wv2.x * hv2.x; a1 += wv2.y * hv2.y;
        a2 += wv2.z * hv2.z; a3 += wv2.w * hv2.w;
      }
      acc += (a0 + a1) + (a2 + a3);
    }
    gs[q * 64 + m * 8 + jj] = acc;
    __syncthreads();

    // ---- pointwise LSTM cell update (64 threads own (m,j) pairs) ----
    if (tid < 64) {
      const int mm = tid >> 3, j2 = tid & 7;
      const float gi = gs[tid];
      const float gf = gs[64 + tid];
      const float gg = gs[128 + tid];
      const float go = gs[192 + tid];
      float c = sigm(gf) * cs[tid] + sigm(gi) * tanhf(gg);
      cs[tid] = c;
      const float h = sigm(go) * tanhf(c);
      float* ob = is1 ? h2b : h1b;
      __hip_atomic_store(ob + (size_t)(t + 1) * 2048 + mm * 256 + jb + j2, h,
                         __ATOMIC_RELAXED, __HIP_MEMORY_SCOPE_AGENT);
    }
    __syncthreads();
    // ---- release ----
    if (tid == 0) {
      __threadfence();
      __hip_atomic_fetch_add(is1 ? &cnt1[t] : &cnt0[t], 1u, __ATOMIC_RELEASE,
                             __HIP_MEMORY_SCOPE_AGENT);
    }
  }
}

// ---------------------------------------------------------------------------
// Kernel 5: FC head  out[8][20000] = tanh(h2[49]) @ fcW^T + fcb
// ---------------------------------------------------------------------------
__global__ __launch_bounds__(256) void fc_kernel(
    const float* __restrict__ h2last, const float* __restrict__ fcW,
    const float* __restrict__ fcb, float* __restrict__ out) {
  __shared__ float tl[2048];
  const int tid = threadIdx.x;
  for (int i = tid; i < 2048; i += 256) tl[i] = tanhf(h2last[i]);
  __syncthreads();
  const int nidx = blockIdx.x * 256 + tid;
  if (nidx >= S_ * N_ * F_) return;
  float accv[8];
#pragma unroll
  for (int m2 = 0; m2 < 8; ++m2) accv[m2] = 0.f;
  const float* wr = fcW + (size_t)nidx * 256;
  for (int k = 0; k < 256; k += 4) {
    float4 w4 = *(const float4*)(wr + k);
#pragma unroll
    for (int m2 = 0; m2 < 8; ++m2) {
      float4 t4 = *(const float4*)&tl[m2 * 256 + k];
      accv[m2] += w4.x * t4.x + w4.y * t4.y + w4.z * t4.z + w4.w * t4.w;
    }
  }
  const float bv = fcb[nidx];
#pragma unroll
  for (int m2 = 0; m2 < 8; ++m2) out[(size_t)m2 * (S_ * N_ * F_) + nidx] = accv[m2] + bv;
}

// ---------------------------------------------------------------------------
// Launch: workspace layout (floats):
//   Z     @ 0          : 400*32000      = 12,800,000
//   part  @ 12,800,000 : 16*400*1024    =  6,553,600
//   G0    @ 19,353,600 : 400*1024       =    409,600
//   h1b   @ 19,763,200 : 51*2048        =    104,448
//   h2b   @ 19,867,648 : 51*2048        =    104,448
//   flags @ 19,972,096 : 128 uint
// total ~79.9 MB of d_ws
// ---------------------------------------------------------------------------
extern "C" void kernel_launch(void* const* d_in, const int* in_sizes, int n_in,
                              void* d_out, int out_size, void* d_ws, size_t ws_size,
                              hipStream_t stream) {
  const float* x    = (const float*)d_in[0];
  const int*   ei   = (const int*)d_in[1];
  const float* ew   = (const float*)d_in[2];
  const float* Wg   = (const float*)d_in[3];
  const float* bg   = (const float*)d_in[4];
  const float* Wih0 = (const float*)d_in[5];
  const float* Whh0 = (const float*)d_in[6];
  const float* bih0 = (const float*)d_in[7];
  const float* bhh0 = (const float*)d_in[8];
  const float* Wih1 = (const float*)d_in[9];
  const float* Whh1 = (const float*)d_in[10];
  const float* bih1 = (const float*)d_in[11];
  const float* bhh1 = (const float*)d_in[12];
  const float* fcW  = (const float*)d_in[13];
  const float* fcb  = (const float*)d_in[14];
  float* out = (float*)d_out;
  float* ws = (float*)d_ws;

  float* Z    = ws;
  float* part = ws + 12800000;
  float* G0   = ws + 19353600;
  float* h1b  = ws + 19763200;
  float* h2b  = ws + 19867648;
  unsigned* cnt0 = (unsigned*)(ws + 19972096);
  unsigned* cnt1 = cnt0 + 64;

  // zero h-state slot0 + flags every call (ws is re-poisoned by harness)
  hipMemsetAsync(h1b, 0, (size_t)(104448 * 2 + 128) * sizeof(float), stream);

  gcn_kernel<<<R_ * 2, 1024, 0, stream>>>(x, ei, ew, Wg, bg, Z);
  gemm_ih<<<dim3(4, 8, KS_), 256, 0, stream>>>(Z, Wih0, part);
  reduce_kernel<<<(R_ * NG_ + 255) / 256, 256, 0, stream>>>(part, bih0, bhh0, G0);
  recur_kernel<<<64, 256, 0, stream>>>(G0, Whh0, Wih1, Whh1, bih1, bhh1, h1b,
                                       h2b, cnt0, cnt1);
  fc_kernel<<<(S_ * N_ * F_ + 255) / 256, 256, 0, stream>>>(h2b + 50 * 2048,
                                                            fcW, fcb, out);
}